// Round 14
// baseline (213.673 us; speedup 1.0000x reference)
//
#include <hip/hip_runtime.h>

// MHSA matched-filter encode, bit-exact replication of the fp32 reference.
// 1 row per wave; window element j on lane (tid&15), replicated x4.
// Wall = 2048 x per-step dependency chain (1 wave/SIMD => all dependent
// latency, SGPR hazards and branch bubbles exposed).
//
// Ladder: r4 161 cyc/step -> r8 146 (pinned prefetch + ballot entry) ->
// r13 137 (carried t, spec slide) ; W=4 always-paid speculation = 283
// (r5, r12) REJECTED. Model: readlane link ~30-35 cyc, branch ~25.
//
// Round-14: W=2 pay-for-average speculation.
//  - Branchless depth<=1: e0 = max(rl(t,0),0); e1 = e0 + rl(t1,1) with
//    t1 = max(fv-w1,0), w1 = v-fv speculated off-chain. k1 = e0<=0.5
//    (= out[i]); k2 = e1<=0.5 gates the rare cold path. Monotone err:
//    if k1 false, e1 = e0 + (junk>=0) > 0.5 => k2 false automatically,
//    so the speculative t1 can never corrupt a decision.
//  - Next state (v,t) speculated BOTH ways off-chain (slide of v and of
//    w1, and their fv-.), picked by one cndmask each => inter-step chain
//    is rl -> cmp -> cndmask -> (next) rl.
//  - Cold path (~35% of steps): r8's PROVEN serial adaptive loop,
//    entered with v=w1, err=e1, continuing at r=2 (decrement #2 at top).
//    Identical op sequence to reference.
// Kept: PIN4 pinned chunk-ahead prefetch (r8-proven), carried t (r13).
//
// Exactness: every window value = same repeated fp32 subs as reference;
// err = literal sequential fp32 prefix; fmax(f-d,0) bit-equivalent to
// where(d<f, f-d, 0) (+/-0 neutral added to err>=+0).

constexpr int NN = 2048;   // row length
constexpr int NBLK = 512;  // rows

__device__ __forceinline__ float f_readlane(float v, int lane) {
    return __int_as_float(__builtin_amdgcn_readlane(__float_as_int(v), lane));
}

// Slide window one toward lane 0: lane i <- lane i+1 within each 16-lane DPP
// row (row_shl:1); lane 15 (invalid source, bound_ctrl=false) keeps `fill`.
__device__ __forceinline__ float f_slide(float src, float fill) {
    return __int_as_float(__builtin_amdgcn_update_dpp(
        __float_as_int(fill), __float_as_int(src),
        0x101 /* row_shl:1 */, 0xF, 0xF, false));
}

// Force 4x float4 to be materialized in VGPRs HERE (defeats load sinking).
#define PIN4(a, b, c, d)                                                   \
    asm volatile("" : "+v"(a.x), "+v"(a.y), "+v"(a.z), "+v"(a.w),          \
                      "+v"(b.x), "+v"(b.y), "+v"(b.z), "+v"(b.w),          \
                      "+v"(c.x), "+v"(c.y), "+v"(c.z), "+v"(c.w),          \
                      "+v"(d.x), "+v"(d.y), "+v"(d.z), "+v"(d.w))

__global__ __launch_bounds__(64) void mhsa_kernel(const float* __restrict__ data,
                                                  const float* __restrict__ filt,
                                                  float* __restrict__ out) {
    __shared__ float lrow[NN + 32];  // +32: last chunk's prefetch overruns
    const int row = blockIdx.x;
    const int tid = threadIdx.x;
    const int j = tid & 15;

    const float* rp = data + (size_t)row * NN;
    float* op = out + (size_t)row * NN;

    // Stage row into LDS (read-only thereafter; window state lives in regs).
    const float4* rp4 = (const float4*)rp;
    float4* l4 = (float4*)lrow;
#pragma unroll
    for (int k = 0; k < NN / 4 / 64; ++k)  // 8 x float4 per thread
        l4[tid + 64 * k] = rp4[tid + 64 * k];
    if (tid < 8) l4[NN / 4 + tid] = make_float4(0.f, 0.f, 0.f, 0.f);  // pad
    __syncthreads();

    const float fv = filt[j] * 0.2f;  // f = filter * NEW_AMP (exact, 1 mul)
    float v = lrow[j];                // window element j at step i=0
    float t = fv - v;                 // carried raw link-0 term argument

    // Current chunk's 16 injection elements (row[16..31]), pinned in regs.
    float4 n0 = l4[4], n1 = l4[5], n2 = l4[6], n3 = l4[7];
    PIN4(n0, n1, n2, n3);

    for (int ib = 0; ib < NN - 16; ib += 16) {
        // Prefetch NEXT chunk's injection elements (row[ib+32 .. ib+47]).
        const float4* pf = (const float4*)(lrow + ib + 32);
        float4 p0 = pf[0], p1 = pf[1], p2 = pf[2], p3 = pf[3];
        PIN4(p0, p1, p2, p3);

        unsigned obits = 0;
#pragma unroll
        for (int s = 0; s < 16; ++s) {
            // Static (post-unroll) component pick of this step's fill value.
            const float4 q = (s < 4) ? n0 : (s < 8) ? n1 : (s < 12) ? n2 : n3;
            const int c = s & 3;
            const float nxt = (c == 0) ? q.x : (c == 1) ? q.y
                            : (c == 2) ? q.z : q.w;

            // ---- speculative, off the err chain ----
            float w1   = v - fv;               // decrement #1 (if k1)
            float t1   = fmaxf(fv - w1, 0.0f); // link-1 term (if k1)
            float vs_a = f_slide(v,  nxt);     // next v if !k1
            float vs_b = f_slide(w1, nxt);     // next v if k1 && !k2
            float ts_a = fv - vs_a;            // next t candidates
            float ts_b = fv - vs_b;

            // ---- the err chain (branchless depth <= 1) ----
            float e0 = fmaxf(f_readlane(t, 0), 0.0f);  // literal err after j=0
            float e1 = e0 + f_readlane(t1, 1);         // err after j=1 (if k1)
            const bool k1 = (e0 <= 0.5f);              // out[i]
            obits |= k1 ? (1u << s) : 0u;

            if (__builtin_expect(e1 <= 0.5f, 0)) {
                // Cold (~35%): >=2 alive links. v=w1 (1 decrement done),
                // err=e1; continue with r8's proven serial adaptive loop.
                v = w1;
                float err = e1;
#pragma unroll 1
                for (int r = 2; r <= 16; ++r) {
                    v = v - fv;          // decrement #r (prev cond true)
                    if (r == 16) break;  // j=15 cond true: decrement only
                    float tr = fmaxf(fv - v, 0.0f);
                    err += f_readlane(tr, r);
                    if (!(err <= 0.5f)) break;
                }
                v = f_slide(v, nxt);
                t = fv - v;
            } else {
                // Common: pick precomputed next state with one cndmask each.
                v = k1 ? vs_b : vs_a;
                t = k1 ? ts_b : ts_a;
            }
        }
        // 16 outputs; replica groups store duplicates (benign).
        op[ib + j] = ((obits >> j) & 1u) ? 1.0f : 0.0f;

        n0 = p0; n1 = p1; n2 = p2; n3 = p3;
    }

    // Step i = 2032 (last fits step): carried t == fv - v for this window.
    {
        float v0 = (f_readlane(t, 0) <= 0.5f) ? 1.0f : 0.0f;
        // i = 2033..2047: fits=false -> err stays 0 -> out = 1.
        op[(NN - 16) + j] = (j == 0) ? v0 : 1.0f;
    }
}

extern "C" void kernel_launch(void* const* d_in, const int* in_sizes, int n_in,
                              void* d_out, int out_size, void* d_ws, size_t ws_size,
                              hipStream_t stream) {
    const float* data = (const float*)d_in[0];  // [512, 2048] f32
    const float* filt = (const float*)d_in[1];  // [16] f32
    float* out = (float*)d_out;                 // [512, 2048] f32
    (void)in_sizes; (void)n_in; (void)out_size; (void)d_ws; (void)ws_size;
    mhsa_kernel<<<dim3(NBLK), dim3(64), 0, stream>>>(data, filt, out);
}